// Round 12
// baseline (235.304 us; speedup 1.0000x reference)
//
#include <hip/hip_runtime.h>
#include <math.h>

#define N_NODES 10000
#define E_EDGES 160000
#define S_DIM 512
#define QKV3 (3*S_DIM)   // 1536
#define V_DIM 128
#define VQKV3 (3*V_DIM)  // 384
#define H_HEADS 8
#define R_BASIS 32
#define HD_DIM 64
#define NV3 (V_DIM*3)    // 384
#define KV8P 896         // int8 row: 512 scalar + 384 vector

typedef _Float16 f16;
typedef f16 f16x8 __attribute__((ext_vector_type(8)));
typedef float f32x4 __attribute__((ext_vector_type(4)));

static __device__ __forceinline__ float h2f(unsigned short u) {
  f16 h; __builtin_memcpy(&h, &u, 2); return (float)h;
}
static __device__ __forceinline__ unsigned short f2h(float f) {
  f16 h = (f16)f; unsigned short u; __builtin_memcpy(&u, &h, 2); return u;
}
static __device__ __forceinline__ float wave_max(float v) {
  #pragma unroll
  for (int o = 32; o > 0; o >>= 1) v = fmaxf(v, __shfl_xor(v, o, 64));
  return v;
}

#if defined(__has_builtin)
#if __has_builtin(__builtin_amdgcn_sdot4)
#define SDOT4(a, b, c) __builtin_amdgcn_sdot4((int)(a), (int)(b), (c), false)
#endif
#endif
#ifndef SDOT4
static __device__ __forceinline__ int sdot4_sw(unsigned int a, unsigned int b, int c) {
  #pragma unroll
  for (int j = 0; j < 4; ++j)
    c += (int)(char)((a >> (8 * j)) & 0xff) * (int)(char)((b >> (8 * j)) & 0xff);
  return c;
}
#define SDOT4(a, b, c) sdot4_sw((a), (b), (c))
#endif

// async global->LDS, 16B per lane; dest must be lane-linear (wavebase + lane*16)
static __device__ __forceinline__ void glds16(const unsigned short* g, unsigned short* l) {
  __builtin_amdgcn_global_load_lds(
      (const __attribute__((address_space(1))) unsigned int*)g,
      (__attribute__((address_space(3))) unsigned int*)l, 16, 0, 0);
}

// ------- fused prep: f32->f16 scalars | edge count | bias concat -------
__global__ __launch_bounds__(256) void prep_kernel(
    const float* __restrict__ scalars, unsigned short* __restrict__ Af16,
    const int* __restrict__ ei, int* __restrict__ counts,
    const float* __restrict__ bq, const float* __restrict__ bk,
    const float* __restrict__ bv, float* __restrict__ bias_cat)
{
  int b = blockIdx.x, t = threadIdx.x;
  if (b < 5000) {
    int i = b * 256 + t;
    float4 v = reinterpret_cast<const float4*>(scalars)[i];
    ushort4 o;
    o.x = f2h(v.x); o.y = f2h(v.y); o.z = f2h(v.z); o.w = f2h(v.w);
    reinterpret_cast<ushort4*>(Af16)[i] = o;
  } else if (b < 5625) {
    int e = (b - 5000) * 256 + t;
    if (e < E_EDGES) atomicAdd(&counts[ei[e]], 1);
  } else {
    int c = (b - 5625) * 256 + t;
    if (c < QKV3)
      bias_cat[c] = (c < 512) ? bq[c] : (c < 1024) ? bk[c - 512] : bv[c - 1024];
  }
}

// ------- 4 weight transposes in one launch: z=0..2 -> cat dst, z=3 -> Do -------
__global__ __launch_bounds__(256) void transpose4_kernel(
    const float* __restrict__ W0, const float* __restrict__ W1,
    const float* __restrict__ W2, const float* __restrict__ W3,
    unsigned short* __restrict__ Dcat, unsigned short* __restrict__ Do, int D)
{
  __shared__ float t[32][33];
  int z = blockIdx.z;
  const float* W = (z == 0) ? W0 : (z == 1) ? W1 : (z == 2) ? W2 : W3;
  unsigned short* dst = (z < 3) ? Dcat + (size_t)z * D * D : Do;
  int n0 = blockIdx.x * 32, k0 = blockIdx.y * 32;
  int x = threadIdx.x, y = threadIdx.y;   // 32 x 8
  #pragma unroll
  for (int j = 0; j < 32; j += 8)
    t[y + j][x] = W[(size_t)(k0 + y + j) * D + n0 + x];
  __syncthreads();
  #pragma unroll
  for (int j = 0; j < 32; j += 8)
    dst[(size_t)(n0 + y + j) * D + k0 + x] = f2h(t[x][y + j]);
}

// ---------------- vectors [n][128][3] f32 -> VT [(n*3+i)][128] f16 ----------------
__global__ __launch_bounds__(128) void vec_transpose_kernel(
    const float* __restrict__ vecs, unsigned short* __restrict__ VT)
{
  __shared__ float l[NV3];
  int n = blockIdx.x, t = threadIdx.x;
  #pragma unroll
  for (int j = 0; j < 3; ++j) l[t + j * 128] = vecs[(size_t)n * NV3 + t + j * 128];
  __syncthreads();
  #pragma unroll
  for (int i = 0; i < 3; ++i)
    VT[((size_t)n * 3 + i) * V_DIM + t] = f2h(l[t * 3 + i]);
}

// ---------------- f16 MFMA GEMM (verified fast, round 5) ----------------
__global__ __launch_bounds__(256) void gemm_f16_kernel(
    const unsigned short* __restrict__ A, const unsigned short* __restrict__ Bt,
    const float* __restrict__ bias, float* __restrict__ Cf,
    unsigned short* __restrict__ Ch, int M, int K, int Nn)
{
  __shared__ unsigned short lds[2][2][128 * 32];
  int tid = threadIdx.x;
  int wid = tid >> 6, lane = tid & 63;
  int wr = wid >> 1, wc = wid & 1;
  int row0 = blockIdx.y * 128, col0 = blockIdx.x * 128;

  int r0 = tid >> 2, s0 = tid & 3;
  int r1 = r0 + 64;
  int sw0 = (r0 >> 1) & 3;
  int aoff = (s0 ^ sw0) * 8;
  int gra0 = row0 + r0; if (gra0 >= M) gra0 = M - 1;
  int gra1 = row0 + r1; if (gra1 >= M) gra1 = M - 1;
  const unsigned short* ag0 = A + (size_t)gra0 * K + aoff;
  const unsigned short* ag1 = A + (size_t)gra1 * K + aoff;
  const unsigned short* bg0 = Bt + (size_t)(col0 + r0) * K + aoff;
  const unsigned short* bg1 = Bt + (size_t)(col0 + r1) * K + aoff;

  f32x4 acc[4][4];
  #pragma unroll
  for (int m = 0; m < 4; ++m)
    #pragma unroll
    for (int n = 0; n < 4; ++n) acc[m][n] = (f32x4){0.f, 0.f, 0.f, 0.f};

  int lr = lane & 15, lq = lane >> 4;
  int slot = (lq ^ ((lr >> 1) & 3)) * 8;
  int aro[4], bro[4];
  #pragma unroll
  for (int m = 0; m < 4; ++m) aro[m] = (wr * 64 + m * 16 + lr) * 32 + slot;
  #pragma unroll
  for (int n = 0; n < 4; ++n) bro[n] = (wc * 64 + n * 16 + lr) * 32 + slot;

  int nk = K >> 5;
  glds16(ag0, &lds[0][0][tid * 8]);
  glds16(ag1, &lds[0][0][(tid + 256) * 8]);
  glds16(bg0, &lds[0][1][tid * 8]);
  glds16(bg1, &lds[0][1][(tid + 256) * 8]);
  __syncthreads();

  for (int t = 0; t < nk; ++t) {
    int cur = t & 1;
    if (t + 1 < nk) {
      int ko = (t + 1) << 5;
      glds16(ag0 + ko, &lds[cur ^ 1][0][tid * 8]);
      glds16(ag1 + ko, &lds[cur ^ 1][0][(tid + 256) * 8]);
      glds16(bg0 + ko, &lds[cur ^ 1][1][tid * 8]);
      glds16(bg1 + ko, &lds[cur ^ 1][1][(tid + 256) * 8]);
    }
    const unsigned short* Ab = lds[cur][0];
    const unsigned short* Bb = lds[cur][1];
    f16x8 af[4], bf[4];
    #pragma unroll
    for (int m = 0; m < 4; ++m) af[m] = *reinterpret_cast<const f16x8*>(Ab + aro[m]);
    #pragma unroll
    for (int n = 0; n < 4; ++n) bf[n] = *reinterpret_cast<const f16x8*>(Bb + bro[n]);
    #pragma unroll
    for (int m = 0; m < 4; ++m)
      #pragma unroll
      for (int n = 0; n < 4; ++n)
        acc[m][n] = __builtin_amdgcn_mfma_f32_16x16x32_f16(af[m], bf[n], acc[m][n], 0, 0, 0);
    __syncthreads();
  }

  float bcol[4];
  #pragma unroll
  for (int n = 0; n < 4; ++n)
    bcol[n] = bias ? bias[col0 + wc * 64 + n * 16 + lr] : 0.f;
  int rl = tid >> 3, cc = (tid & 7) * 16;

  if (Cf) {
    float* cst = reinterpret_cast<float*>(&lds[0][0][0]);
    #pragma unroll
    for (int m = 0; m < 4; ++m) {
      __syncthreads();
      #pragma unroll
      for (int n = 0; n < 4; ++n)
        #pragma unroll
        for (int j = 0; j < 4; ++j)
          cst[(wr * 16 + lq * 4 + j) * 128 + wc * 64 + n * 16 + lr] = acc[m][n][j] + bcol[n];
      __syncthreads();
      int row = row0 + (rl >> 4) * 64 + m * 16 + (rl & 15);
      if (row < M) {
        float4* dst = reinterpret_cast<float4*>(Cf + (size_t)row * Nn + col0 + cc);
        const float4* src = reinterpret_cast<const float4*>(cst + rl * 128 + cc);
        dst[0] = src[0]; dst[1] = src[1]; dst[2] = src[2]; dst[3] = src[3];
      }
    }
  } else {
    unsigned short* csth = &lds[0][0][0];
    #pragma unroll
    for (int m = 0; m < 4; ++m) {
      __syncthreads();
      #pragma unroll
      for (int n = 0; n < 4; ++n)
        #pragma unroll
        for (int j = 0; j < 4; ++j)
          csth[(wr * 16 + lq * 4 + j) * 128 + wc * 64 + n * 16 + lr] = f2h(acc[m][n][j] + bcol[n]);
      __syncthreads();
      int row = row0 + (rl >> 4) * 64 + m * 16 + (rl & 15);
      if (row < M) {
        int4* dst = reinterpret_cast<int4*>(Ch + (size_t)row * Nn + col0 + cc);
        const int4* src = reinterpret_cast<const int4*>(csth + rl * 128 + cc);
        dst[0] = src[0]; dst[1] = src[1];
      }
    }
  }
}

// -------- pack Q,K into int8 rows [n][896] with per-node scales (2/node) --------
__global__ __launch_bounds__(256) void pack_i8_kernel(
    const unsigned short* __restrict__ qkv_s, const unsigned short* __restrict__ qkv_v,
    char* __restrict__ q8, char* __restrict__ k8, float* __restrict__ scales)
{
  __shared__ float am[224];
  __shared__ float inv_sh[2];
  int n = blockIdx.x, t = threadIdx.x;
  float va[8];

  if (t < 224) {
    int r = t / 112, j = t - r * 112;
    int c = j * 8;
    const unsigned short* src;
    if (c < 512) {
      src = qkv_s + (size_t)n * QKV3 + r * 512 + c;
    } else {
      int cc = c - 512, i = cc >> 7, w = cc & 127;
      src = qkv_v + ((size_t)n * 3 + i) * VQKV3 + r * 128 + w;
    }
    int4 sv = *reinterpret_cast<const int4*>(src);
    union { int4 x; unsigned short u[8]; } us; us.x = sv;
    float m = 0.f;
    #pragma unroll
    for (int q = 0; q < 8; ++q) { va[q] = h2f(us.u[q]); m = fmaxf(m, fabsf(va[q])); }
    am[t] = m;
  }
  __syncthreads();

  int lane = t & 63, wid = t >> 6;
  if (wid < 2) {
    int basec = wid * 112;
    float m = am[basec + lane];
    if (lane < 48) m = fmaxf(m, am[basec + 64 + lane]);
    m = wave_max(m);
    if (lane == 0) {
      m = fmaxf(m, 1e-8f);
      scales[2 * n + wid] = m * (1.f / 127.f);
      inv_sh[wid] = 127.f / m;
    }
  }
  __syncthreads();

  if (t < 224) {
    int r = t / 112, j = t - r * 112;
    float inv = inv_sh[r];
    unsigned int b0 = 0, b1 = 0;
    #pragma unroll
    for (int q = 0; q < 4; ++q) {
      int x = __float2int_rn(va[q] * inv);
      b0 |= ((unsigned)(x & 0xff)) << (8 * q);
    }
    #pragma unroll
    for (int q = 0; q < 4; ++q) {
      int x = __float2int_rn(va[4 + q] * inv);
      b1 |= ((unsigned)(x & 0xff)) << (8 * q);
    }
    char* dst = (r == 0 ? q8 : k8) + (size_t)n * KV8P + j * 8;
    uint2 o; o.x = b0; o.y = b1;
    *reinterpret_cast<uint2*>(dst) = o;
  }
}

// -------- single-block exclusive scan --------
__global__ __launch_bounds__(1024) void scan_kernel(const int* __restrict__ counts,
                                                    int* __restrict__ offs, int n) {
  __shared__ int wsum[16];
  __shared__ int carry_s;
  int tid = threadIdx.x;
  int lane = tid & 63, w = tid >> 6;
  if (tid == 0) carry_s = 0;
  __syncthreads();
  for (int base = 0; base < n; base += 1024) {
    int i = base + tid;
    int v = (i < n) ? counts[i] : 0;
    int x = v;
    #pragma unroll
    for (int o = 1; o < 64; o <<= 1) {
      int t = __shfl_up(x, o, 64);
      if (lane >= o) x += t;
    }
    if (lane == 63) wsum[w] = x;
    __syncthreads();
    if (w == 0 && lane < 16) {
      int t = wsum[lane];
      #pragma unroll
      for (int o = 1; o < 16; o <<= 1) {
        int u = __shfl_up(t, o, 64);
        if (lane >= o) t += u;
      }
      wsum[lane] = t;
    }
    __syncthreads();
    int incl = x + ((w > 0) ? wsum[w - 1] : 0);
    int c = carry_s;
    __syncthreads();
    if (i < n) offs[i] = c + incl - v;
    if (tid == 1023) carry_s = c + incl;
    __syncthreads();
  }
  if (tid == 0) offs[n] = carry_s;
}

// -------- scatter: CSR-ordered record (d, row, col) --------
__global__ void scatter_kernel(const int* __restrict__ ei, const float* __restrict__ edge_vec,
                               const int* __restrict__ offs, int* __restrict__ cursor,
                               int4* __restrict__ rec) {
  int e = blockIdx.x * 256 + threadIdx.x;
  if (e < E_EDGES) {
    int row = ei[e], col = ei[E_EDGES + e];
    int pos = offs[row] + atomicAdd(&cursor[row], 1);
    float ex = edge_vec[(size_t)e * 3 + 0];
    float ey = edge_vec[(size_t)e * 3 + 1];
    float ez = edge_vec[(size_t)e * 3 + 2];
    float d = sqrtf(ex * ex + ey * ey + ez * ez);
    rec[pos] = make_int4(__float_as_int(d), row, col, 0);
  }
}

// -------- per-edge logits: CSR order, 8 lanes/edge, int8 sdot4, fused bessel --------
__global__ __launch_bounds__(256, 4) void edge_logits_kernel(
    const char* __restrict__ q8, const char* __restrict__ k8,
    const float* __restrict__ scales, const int4* __restrict__ rec,
    const float* __restrict__ W_edge, const float* __restrict__ b_edge,
    float* __restrict__ logits)
{
  __shared__ float Wl[R_BASIS * H_HEADS];
  Wl[threadIdx.x] = W_edge[threadIdx.x];
  __syncthreads();

  int lane = threadIdx.x & 63;
  int wv = threadIdx.x >> 6;
  int g = lane >> 3, h = lane & 7;
  int pos = blockIdx.x * 32 + wv * 8 + g;
  int4 r = rec[pos];                 // 8 lanes load same 16B -> broadcast
  float d = __int_as_float(r.x);
  int row = r.y, col = r.z;

  // issue all gathers first (latency batching)
  const char* qp = q8 + (size_t)row * KV8P;
  const char* kp = k8 + (size_t)col * KV8P;
  uint4 qa[4], ka[4], qv[3], kv[3];
  #pragma unroll
  for (int rr = 0; rr < 4; ++rr)
    ka[rr] = *reinterpret_cast<const uint4*>(kp + h * HD_DIM + rr * 16);
  #pragma unroll
  for (int rr = 0; rr < 3; ++rr)
    kv[rr] = *reinterpret_cast<const uint4*>(kp + 512 + h * 48 + rr * 16);
  #pragma unroll
  for (int rr = 0; rr < 4; ++rr)
    qa[rr] = *reinterpret_cast<const uint4*>(qp + h * HD_DIM + rr * 16);
  #pragma unroll
  for (int rr = 0; rr < 3; ++rr)
    qv[rr] = *reinterpret_cast<const uint4*>(qp + 512 + h * 48 + rr * 16);

  float sq = scales[2 * row + 0];
  float sk = scales[2 * col + 1];

  int dsum = 0;
  #pragma unroll
  for (int rr = 0; rr < 4; ++rr) {
    dsum = SDOT4(qa[rr].x, ka[rr].x, dsum);
    dsum = SDOT4(qa[rr].y, ka[rr].y, dsum);
    dsum = SDOT4(qa[rr].z, ka[rr].z, dsum);
    dsum = SDOT4(qa[rr].w, ka[rr].w, dsum);
  }
  int dvec = 0;
  #pragma unroll
  for (int rr = 0; rr < 3; ++rr) {
    dvec = SDOT4(qv[rr].x, kv[rr].x, dvec);
    dvec = SDOT4(qv[rr].y, kv[rr].y, dvec);
    dvec = SDOT4(qv[rr].z, kv[rr].z, dvec);
    dvec = SDOT4(qv[rr].w, kv[rr].w, dvec);
  }
  dvec += __shfl_xor(dvec, 1, 64);
  dvec += __shfl_xor(dvec, 2, 64);
  dvec += __shfl_xor(dvec, 4, 64);

  float att = sq * sk * ((float)dsum + 0.57735026918962576f * (float)dvec);

  // bessel + edge MLP (4-way-ILP sin recurrence), lane = head column
  float th = d * 0.31415926535897932f;  // pi*d/10
  float s1 = __sinf(th), c1 = __cosf(th);
  float s2 = 2.f * s1 * c1,         c2 = fmaf(c1, c1, -s1 * s1);
  float s3 = fmaf(s2, c1, c2 * s1), c3 = fmaf(c2, c1, -s2 * s1);
  float s4 = 2.f * s2 * c2,         c4 = fmaf(c2, c2, -s2 * s2);
  float sr[4] = {s1, s2, s3, s4};
  float cr[4] = {c1, c2, c3, c4};
  float acc = 0.f;
  #pragma unroll
  for (int t = 0; t < 8; ++t) {
    #pragma unroll
    for (int j = 0; j < 4; ++j) {
      acc = fmaf(sr[j], Wl[(t * 4 + j) * H_HEADS + h], acc);
      float sn = fmaf(sr[j], c4, cr[j] * s4);
      cr[j] = fmaf(cr[j], c4, -sr[j] * s4);
      sr[j] = sn;
    }
  }
  float cut = (d < 10.f) ? 0.5f * (c1 + 1.f) : 0.f;
  float eah = fmaf(acc, cut / fmaxf(d, 1e-8f), b_edge[h]);

  logits[(size_t)pos * H_HEADS + h] = (att + eah) * 0.125f;
}

// -------- per-node softmax + aggregation (f16 V gather, conflict-free) --------
#define MAXDEG 128
__global__ __launch_bounds__(256) void agg_kernel(
    const float* __restrict__ logits, const int4* __restrict__ rec,
    const unsigned short* __restrict__ qkv_s, const unsigned short* __restrict__ qkv_v,
    const int* __restrict__ offs,
    unsigned short* __restrict__ out_s, unsigned short* __restrict__ out_v)
{
  __shared__ float buf[3584];        // attn in [0,1024); reduce uses [0,3584)
  __shared__ float av_lds[MAXDEG];
  __shared__ int col_lds[MAXDEG];
  __shared__ float m_sh[H_HEADS], inv_sh[H_HEADS];

  int n = blockIdx.x;
  int beg = offs[n];
  int deg = offs[n + 1] - beg;
  if (deg > MAXDEG) deg = MAXDEG;    // deg ~ Poisson(16); max ~45 for this graph
  int tid = threadIdx.x;
  int lane = tid & 63, wv = tid >> 6;
  int g = lane >> 3, h = lane & 7;

  // Phase 0: stage logits + cols (contiguous, coalesced)
  int cnt8 = deg * 8;
  for (int j = tid; j < cnt8; j += 256) buf[j] = logits[(size_t)beg * 8 + j];
  for (int i = tid; i < deg; i += 256) col_lds[i] = rec[beg + i].z;
  __syncthreads();

  // Phase B: softmax on wave 0 (lane=(g,h) -> contiguous addr, conflict-free)
  if (wv == 0) {
    float m = -INFINITY;
    for (int i = g; i < deg; i += 8) m = fmaxf(m, buf[i * 8 + h]);
    m = fmaxf(m, __shfl_xor(m, 8, 64));
    m = fmaxf(m, __shfl_xor(m, 16, 64));
    m = fmaxf(m, __shfl_xor(m, 32, 64));

    float s = 0.f;
    for (int i = g; i < deg; i += 8) {
      float w = __expf(buf[i * 8 + h] - m);
      buf[i * 8 + h] = w;
      s += w;
    }
    s += __shfl_xor(s, 8, 64);
    s += __shfl_xor(s, 16, 64);
    s += __shfl_xor(s, 32, 64);
    float inv = 1.f / (s + 1e-9f);
    if (lane < 8) { m_sh[lane] = m; inv_sh[lane] = inv; }

    for (int i = g; i < deg; i += 8) {
      float t = buf[i * 8 + h] * inv;
      t += __shfl_xor(t, 1, 64);
      t += __shfl_xor(t, 2, 64);
      t += __shfl_xor(t, 4, 64);
      if (h == 0) av_lds[i] = 0.125f * t;
    }
  }
  __syncthreads();

  // Phase C: V-accumulate (4 waves, edges i ≡ wv mod 4), f16 V from qkv_s/qkv_v
  int hc = lane >> 3;
  float ih = inv_sh[hc];
  int fv = lane * 8;
  int vi = fv >> 7, vw = fv & 127;   // qkv_v sub-row and offset (for lane<48)
  float accs[8] = {0,0,0,0,0,0,0,0};
  float accv[8] = {0,0,0,0,0,0,0,0};
  auto body = [&](int i) {
    int colv = col_lds[i];
    float wgt = buf[i * 8 + hc] * ih;
    float av = av_lds[i];
    int4 vs = *reinterpret_cast<const int4*>(qkv_s + (size_t)colv * QKV3 + 1024 + lane * 8);
    union { int4 v; unsigned short u[8]; } uv; uv.v = vs;
    #pragma unroll
    for (int j = 0; j < 8; ++j) accs[j] = fmaf(wgt, h2f(uv.u[j]), accs[j]);
    if (lane < 48) {
      int4 vvl = *reinterpret_cast<const int4*>(qkv_v + ((size_t)colv * 3 + vi) * VQKV3 + 256 + vw);
      union { int4 v; unsigned short u[8]; } uv2; uv2.v = vvl;
      #pragma unroll
      for (int j = 0; j < 8; ++j) accv[j] = fmaf(av, h2f(uv2.u[j]), accv[j]);
    }
  };
  int i = wv;
  for (; i + 4 < deg; i += 8) { body(i); body(i + 4); }
  if (i < deg) body(i);
  __syncthreads();

  // Phase D: cross-wave reduce; write-order swizzle (each b128 pair covers all 8 bank quads)
  float* red_s = buf;                // [4][512]
  float* red_v = buf + 2048;         // [4][384]
  int o = ((lane >> 2) & 1) << 2;    // 0 or 4
  *reinterpret_cast<float4*>(&red_s[wv * 512 + lane * 8 + o]) =
    make_float4(accs[o], accs[o+1], accs[o+2], accs[o+3]);
  *reinterpret_cast<float4*>(&red_s[wv * 512 + lane * 8 + (o ^ 4)]) =
    make_float4(accs[o^4], accs[(o^4)+1], accs[(o^4)+2], accs[(o^4)+3]);
  if (lane < 48) {
    *reinterpret_cast<float4*>(&red_v[wv * 384 + lane * 8 + o]) =
      make_float4(accv[o], accv[o+1], accv[o+2], accv[o+3]);
    *reinterpret_cast<float4*>(&red_v[wv * 384 + lane * 8 + (o ^ 4)]) =
      make_float4(accv[o^4], accv[(o^4)+1], accv[(o^4)+2], accv[(o^4)+3]);
  }
  __syncthreads();

  {
    int d0 = 2 * tid;
    float s0 = red_s[d0] + red_s[512 + d0] + red_s[1024 + d0] + red_s[1536 + d0];
    float s1 = red_s[d0+1] + red_s[512 + d0+1] + red_s[1024 + d0+1] + red_s[1536 + d0+1];
    ushort2 ov; ov.x = f2h(s0); ov.y = f2h(s1);
    *reinterpret_cast<ushort2*>(out_s + (size_t)n * S_DIM + d0) = ov;
  }
  if (tid < 192) {
    int d0 = 2 * tid;
    float s0 = red_v[d0] + red_v[384 + d0] + red_v[768 + d0] + red_v[1152 + d0];
    float s1 = red_v[d0+1] + red_v[384 + d0+1] + red_v[768 + d0+1] + red_v[1152 + d0+1];
    ushort2 ov; ov.x = f2h(s0); ov.y = f2h(s1);
    *reinterpret_cast<ushort2*>(out_v + (size_t)n * NV3 + d0) = ov;
  }
}

// -------- merged epilogue: blocks [0,2500) residual+LN; [2500,7500) vec epilogue --------
__global__ __launch_bounds__(256) void epilogue_kernel(
    const float* __restrict__ x0, const float* __restrict__ dx,
    const float* __restrict__ g, const float* __restrict__ b,
    const float* __restrict__ tmpv, const float* __restrict__ bout_v,
    const float* __restrict__ vectors, float* __restrict__ out_s,
    float* __restrict__ out_v)
{
  __shared__ float l[2][NV3];
  int bidx = blockIdx.x;
  if (bidx < 2500) {
    int r = bidx * 4 + (threadIdx.x >> 6);
    int lane = threadIdx.x & 63;
    float x[8];
    float s = 0.f;
    #pragma unroll
    for (int j = 0; j < 8; ++j) {
      int d = lane + j * 64;
      x[j] = x0[(size_t)r * S_DIM + d] + dx[(size_t)r * S_DIM + d];
      s += x[j];
    }
    #pragma unroll
    for (int o = 32; o > 0; o >>= 1) s += __shfl_xor(s, o, 64);
    float mu = s * (1.f / 512.f);
    float vs = 0.f;
    #pragma unroll
    for (int j = 0; j < 8; ++j) { float t = x[j] - mu; vs += t * t; }
    #pragma unroll
    for (int o = 32; o > 0; o >>= 1) vs += __shfl_xor(vs, o, 64);
    float inv = rsqrtf(vs * (1.f / 512.f) + 1e-5f);
    #pragma unroll
    for (int j = 0; j < 8; ++j) {
      int d = lane + j * 64;
      out_s[(size_t)r * S_DIM + d] = (x[j] - mu) * inv * g[d] + b[d];
    }
  } else {
    int half = threadIdx.x >> 7;        // 0/1
    int t = threadIdx.x & 127;
    int n = (bidx - 2500) * 2 + half;
    #pragma unroll
    for (int i = 0; i < 3; ++i)
      l[half][i * 128 + t] = tmpv[((size_t)n * 3 + i) * V_DIM + t];
    __syncthreads();
    #pragma unroll
    for (int c = 0; c < 3; ++c) {
      int j = t + c * 128;      // j = w*3 + i
      int w = j / 3, i = j - 3 * w;
      out_v[(size_t)n * NV3 + j] = l[half][i * 128 + w] + bout_v[w] + vectors[(size_t)n * NV3 + j];
    }
  }
}

extern "C" void kernel_launch(void* const* d_in, const int* in_sizes, int n_in,
                              void* d_out, int out_size, void* d_ws, size_t ws_size,
                              hipStream_t stream)
{
  (void)in_sizes; (void)n_in; (void)out_size; (void)ws_size;
  const float* scalars  = (const float*)d_in[0];
  const float* vectors  = (const float*)d_in[1];
  const float* edge_vec = (const float*)d_in[2];
  const float* Wq_s = (const float*)d_in[3];
  const float* bq_s = (const float*)d_in[4];
  const float* Wk_s = (const float*)d_in[5];
  const float* bk_s = (const float*)d_in[6];
  const float* Wv_s = (const float*)d_in[7];
  const float* bv_s = (const float*)d_in[8];
  const float* Wq_v = (const float*)d_in[9];
  const float* Wk_v = (const float*)d_in[10];
  const float* Wv_v = (const float*)d_in[11];
  const float* Wout_s = (const float*)d_in[12];
  const float* bout_s = (const float*)d_in[13];
  const float* Wout_v = (const float*)d_in[14];
  const float* bout_v = (const float*)d_in[15];
  const float* W_edge = (const float*)d_in[16];
  const float* b_edge = (const float*)d_in[17];
  const float* ln_g = (const float*)d_in[18];
  const float* ln_b = (const float*)d_in[19];
  const int* ei = (const int*)d_in[20];

  float* out = (float*)d_out;
  const size_t NS  = (size_t)N_NODES * S_DIM;     // 5,120,000
  const size_t NVs = (size_t)N_NODES * NV3;       // 3,840,000
  const size_t EH  = (size_t)E_EDGES * H_HEADS;   // 1,280,000
  const size_t WSZ = (size_t)S_DIM * S_DIM;
  const size_t WVZ = (size_t)V_DIM * V_DIM;
  const int MV = N_NODES * 3;

  char* base = (char*)d_ws;
  auto carve = [&](size_t bytes) -> char* {
    char* p = base;
    base += (bytes + 255) & ~(size_t)255;
    return p;
  };
  unsigned short* Af16 = (unsigned short*)carve(NS * 2);    // 10.24MB
  unsigned short* VT0  = (unsigned short*)carve(NVs * 2);   // 7.68MB
  float* tmpv = (float*)Af16;   // alias (15.36MB; Af16+VT0 dead by then)
  unsigned short* qkv_s = (unsigned short*)carve((size_t)N_NODES * QKV3 * 2);   // 30.72MB
  unsigned short* qkv_v = (unsigned short*)carve((size_t)MV * VQKV3 * 2);       // 23.04MB
  unsigned short* outs_pre = (unsigned short*)carve(NS * 2);
  unsigned short* outv_pre = (unsigned short*)carve(NVs * 2);
  float* dx       = (float*)carve(NS * 4);        // 20.48MB
  // q8/k8 alias dx: lifetimes disjoint (pack->agg; dx written by Wout gemm after)
  char* q8 = (char*)dx;                                      // 8.96MB
  char* k8 = q8 + (size_t)N_NODES * KV8P;                    // 8.96MB (17.92 <= 20.48)
  float* logitsS  = (float*)carve(EH * 4);
  int4*  rec      = (int4*)carve((size_t)E_EDGES * 16);      // 2.56MB
  unsigned short* WqkvT  = (unsigned short*)carve(3 * WSZ * 2);
  unsigned short* WoT    = (unsigned short*)carve(WSZ * 2);
  unsigned short* WqkvvT = (unsigned short*)carve(3 * WVZ * 2);
  unsigned short* WovT   = (unsigned short*)carve(WVZ * 2);
  float* bias_cat = (float*)carve(QKV3 * 4);
  float* scales   = (float*)carve(2 * N_NODES * 4);
  int* counts = (int*)carve(N_NODES * 4);
  int* offs   = (int*)carve((N_NODES + 1) * 4);
  int* cursor = (int*)carve(N_NODES * 4);

  hipMemsetAsync(counts, 0, N_NODES * sizeof(int), stream);
  hipMemsetAsync(cursor, 0, N_NODES * sizeof(int), stream);

  // fused prep: f32->f16 scalars | edge count | bias concat
  prep_kernel<<<5631, 256, 0, stream>>>(scalars, Af16, ei, counts,
                                        bq_s, bk_s, bv_s, bias_cat);
  dim3 tBlk(32, 8);
  transpose4_kernel<<<dim3(16, 16, 4), tBlk, 0, stream>>>(Wq_s, Wk_s, Wv_s, Wout_s, WqkvT, WoT, S_DIM);
  transpose4_kernel<<<dim3(4, 4, 4), tBlk, 0, stream>>>(Wq_v, Wk_v, Wv_v, Wout_v, WqkvvT, WovT, V_DIM);
  vec_transpose_kernel<<<N_NODES, 128, 0, stream>>>(vectors, VT0);

  // fused QKV projections
  gemm_f16_kernel<<<dim3(QKV3 / 128, (N_NODES + 127) / 128), 256, 0, stream>>>(
      Af16, WqkvT, bias_cat, nullptr, qkv_s, N_NODES, S_DIM, QKV3);
  gemm_f16_kernel<<<dim3(VQKV3 / 128, (MV + 127) / 128), 256, 0, stream>>>(
      VT0, WqkvvT, nullptr, nullptr, qkv_v, MV, V_DIM, VQKV3);

  // int8 Q/K rows + per-node scales (V stays f16 in qkv_s/qkv_v)
  pack_i8_kernel<<<N_NODES, 256, 0, stream>>>(qkv_s, qkv_v, q8, k8, scales);

  // CSR offsets + CSR-ordered edge records
  scan_kernel<<<1, 1024, 0, stream>>>(counts, offs, N_NODES);
  scatter_kernel<<<(E_EDGES + 255) / 256, 256, 0, stream>>>(ei, edge_vec, offs, cursor, rec);

  // edge logits (int8 sdot4 gathers + fused bessel, CSR order)
  edge_logits_kernel<<<E_EDGES / 32, 256, 0, stream>>>(q8, k8, scales, rec,
                                                       W_edge, b_edge, logitsS);

  // softmax + aggregate (f16 V gather)
  agg_kernel<<<N_NODES, 256, 0, stream>>>(logitsS, rec, qkv_s, qkv_v, offs,
                                          outs_pre, outv_pre);

  // output projections + merged epilogue
  gemm_f16_kernel<<<dim3(S_DIM / 128, (N_NODES + 127) / 128), 256, 0, stream>>>(
      outs_pre, WoT, bout_s, dx, nullptr, N_NODES, S_DIM, S_DIM);
  gemm_f16_kernel<<<dim3(1, (MV + 127) / 128), 256, 0, stream>>>(
      outv_pre, WovT, nullptr, tmpv, nullptr, MV, V_DIM, V_DIM);
  epilogue_kernel<<<7500, 256, 0, stream>>>(scalars, dx, ln_g, ln_b,
                                            tmpv, bout_v, vectors, out, out + NS);
}

// Round 13
// 232.238 us; speedup vs baseline: 1.0132x; 1.0132x over previous
//
#include <hip/hip_runtime.h>
#include <math.h>

#define N_NODES 10000
#define E_EDGES 160000
#define S_DIM 512
#define QKV3 (3*S_DIM)   // 1536
#define V_DIM 128
#define VQKV3 (3*V_DIM)  // 384
#define H_HEADS 8
#define R_BASIS 32
#define HD_DIM 64
#define NV3 (V_DIM*3)    // 384
#define KV8P 896         // int8 row: 512 scalar + 384 vector

typedef _Float16 f16;
typedef f16 f16x8 __attribute__((ext_vector_type(8)));
typedef float f32x4 __attribute__((ext_vector_type(4)));

static __device__ __forceinline__ float h2f(unsigned short u) {
  f16 h; __builtin_memcpy(&h, &u, 2); return (float)h;
}
static __device__ __forceinline__ unsigned short f2h(float f) {
  f16 h = (f16)f; unsigned short u; __builtin_memcpy(&u, &h, 2); return u;
}
static __device__ __forceinline__ float wave_max(float v) {
  #pragma unroll
  for (int o = 32; o > 0; o >>= 1) v = fmaxf(v, __shfl_xor(v, o, 64));
  return v;
}

#if defined(__has_builtin)
#if __has_builtin(__builtin_amdgcn_sdot4)
#define SDOT4(a, b, c) __builtin_amdgcn_sdot4((int)(a), (int)(b), (c), false)
#endif
#endif
#ifndef SDOT4
static __device__ __forceinline__ int sdot4_sw(unsigned int a, unsigned int b, int c) {
  #pragma unroll
  for (int j = 0; j < 4; ++j)
    c += (int)(char)((a >> (8 * j)) & 0xff) * (int)(char)((b >> (8 * j)) & 0xff);
  return c;
}
#define SDOT4(a, b, c) sdot4_sw((a), (b), (c))
#endif

// excess-128 unpack: single v_cvt_f32_ubyteN + fma per element
static __device__ __forceinline__ void fma_u8x4(unsigned int w, float wt, float* acc) {
  acc[0] = fmaf(wt, (float)(w & 0xffu), acc[0]);
  acc[1] = fmaf(wt, (float)((w >> 8) & 0xffu), acc[1]);
  acc[2] = fmaf(wt, (float)((w >> 16) & 0xffu), acc[2]);
  acc[3] = fmaf(wt, (float)((w >> 24) & 0xffu), acc[3]);
}

// async global->LDS, 16B per lane; dest must be lane-linear (wavebase + lane*16)
static __device__ __forceinline__ void glds16(const unsigned short* g, unsigned short* l) {
  __builtin_amdgcn_global_load_lds(
      (const __attribute__((address_space(1))) unsigned int*)g,
      (__attribute__((address_space(3))) unsigned int*)l, 16, 0, 0);
}

// ------- fused prep: f32->f16 scalars | edge count | bias concat -------
__global__ __launch_bounds__(256) void prep_kernel(
    const float* __restrict__ scalars, unsigned short* __restrict__ Af16,
    const int* __restrict__ ei, int* __restrict__ counts,
    const float* __restrict__ bq, const float* __restrict__ bk,
    const float* __restrict__ bv, float* __restrict__ bias_cat)
{
  int b = blockIdx.x, t = threadIdx.x;
  if (b < 5000) {
    int i = b * 256 + t;
    float4 v = reinterpret_cast<const float4*>(scalars)[i];
    ushort4 o;
    o.x = f2h(v.x); o.y = f2h(v.y); o.z = f2h(v.z); o.w = f2h(v.w);
    reinterpret_cast<ushort4*>(Af16)[i] = o;
  } else if (b < 5625) {
    int e = (b - 5000) * 256 + t;
    if (e < E_EDGES) atomicAdd(&counts[ei[e]], 1);
  } else {
    int c = (b - 5625) * 256 + t;
    if (c < QKV3)
      bias_cat[c] = (c < 512) ? bq[c] : (c < 1024) ? bk[c - 512] : bv[c - 1024];
  }
}

// ------- 4 weight transposes in one launch: z=0..2 -> cat dst, z=3 -> Do -------
__global__ __launch_bounds__(256) void transpose4_kernel(
    const float* __restrict__ W0, const float* __restrict__ W1,
    const float* __restrict__ W2, const float* __restrict__ W3,
    unsigned short* __restrict__ Dcat, unsigned short* __restrict__ Do, int D)
{
  __shared__ float t[32][33];
  int z = blockIdx.z;
  const float* W = (z == 0) ? W0 : (z == 1) ? W1 : (z == 2) ? W2 : W3;
  unsigned short* dst = (z < 3) ? Dcat + (size_t)z * D * D : Do;
  int n0 = blockIdx.x * 32, k0 = blockIdx.y * 32;
  int x = threadIdx.x, y = threadIdx.y;   // 32 x 8
  #pragma unroll
  for (int j = 0; j < 32; j += 8)
    t[y + j][x] = W[(size_t)(k0 + y + j) * D + n0 + x];
  __syncthreads();
  #pragma unroll
  for (int j = 0; j < 32; j += 8)
    dst[(size_t)(n0 + y + j) * D + k0 + x] = f2h(t[x][y + j]);
}

// ---------------- vectors [n][128][3] f32 -> VT [(n*3+i)][128] f16 ----------------
__global__ __launch_bounds__(128) void vec_transpose_kernel(
    const float* __restrict__ vecs, unsigned short* __restrict__ VT)
{
  __shared__ float l[NV3];
  int n = blockIdx.x, t = threadIdx.x;
  #pragma unroll
  for (int j = 0; j < 3; ++j) l[t + j * 128] = vecs[(size_t)n * NV3 + t + j * 128];
  __syncthreads();
  #pragma unroll
  for (int i = 0; i < 3; ++i)
    VT[((size_t)n * 3 + i) * V_DIM + t] = f2h(l[t * 3 + i]);
}

// ---------------- f16 MFMA GEMM (verified fast, round 5) ----------------
__global__ __launch_bounds__(256) void gemm_f16_kernel(
    const unsigned short* __restrict__ A, const unsigned short* __restrict__ Bt,
    const float* __restrict__ bias, float* __restrict__ Cf,
    unsigned short* __restrict__ Ch, int M, int K, int Nn)
{
  __shared__ unsigned short lds[2][2][128 * 32];
  int tid = threadIdx.x;
  int wid = tid >> 6, lane = tid & 63;
  int wr = wid >> 1, wc = wid & 1;
  int row0 = blockIdx.y * 128, col0 = blockIdx.x * 128;

  int r0 = tid >> 2, s0 = tid & 3;
  int r1 = r0 + 64;
  int sw0 = (r0 >> 1) & 3;
  int aoff = (s0 ^ sw0) * 8;
  int gra0 = row0 + r0; if (gra0 >= M) gra0 = M - 1;
  int gra1 = row0 + r1; if (gra1 >= M) gra1 = M - 1;
  const unsigned short* ag0 = A + (size_t)gra0 * K + aoff;
  const unsigned short* ag1 = A + (size_t)gra1 * K + aoff;
  const unsigned short* bg0 = Bt + (size_t)(col0 + r0) * K + aoff;
  const unsigned short* bg1 = Bt + (size_t)(col0 + r1) * K + aoff;

  f32x4 acc[4][4];
  #pragma unroll
  for (int m = 0; m < 4; ++m)
    #pragma unroll
    for (int n = 0; n < 4; ++n) acc[m][n] = (f32x4){0.f, 0.f, 0.f, 0.f};

  int lr = lane & 15, lq = lane >> 4;
  int slot = (lq ^ ((lr >> 1) & 3)) * 8;
  int aro[4], bro[4];
  #pragma unroll
  for (int m = 0; m < 4; ++m) aro[m] = (wr * 64 + m * 16 + lr) * 32 + slot;
  #pragma unroll
  for (int n = 0; n < 4; ++n) bro[n] = (wc * 64 + n * 16 + lr) * 32 + slot;

  int nk = K >> 5;
  glds16(ag0, &lds[0][0][tid * 8]);
  glds16(ag1, &lds[0][0][(tid + 256) * 8]);
  glds16(bg0, &lds[0][1][tid * 8]);
  glds16(bg1, &lds[0][1][(tid + 256) * 8]);
  __syncthreads();

  for (int t = 0; t < nk; ++t) {
    int cur = t & 1;
    if (t + 1 < nk) {
      int ko = (t + 1) << 5;
      glds16(ag0 + ko, &lds[cur ^ 1][0][tid * 8]);
      glds16(ag1 + ko, &lds[cur ^ 1][0][(tid + 256) * 8]);
      glds16(bg0 + ko, &lds[cur ^ 1][1][tid * 8]);
      glds16(bg1 + ko, &lds[cur ^ 1][1][(tid + 256) * 8]);
    }
    const unsigned short* Ab = lds[cur][0];
    const unsigned short* Bb = lds[cur][1];
    f16x8 af[4], bf[4];
    #pragma unroll
    for (int m = 0; m < 4; ++m) af[m] = *reinterpret_cast<const f16x8*>(Ab + aro[m]);
    #pragma unroll
    for (int n = 0; n < 4; ++n) bf[n] = *reinterpret_cast<const f16x8*>(Bb + bro[n]);
    #pragma unroll
    for (int m = 0; m < 4; ++m)
      #pragma unroll
      for (int n = 0; n < 4; ++n)
        acc[m][n] = __builtin_amdgcn_mfma_f32_16x16x32_f16(af[m], bf[n], acc[m][n], 0, 0, 0);
    __syncthreads();
  }

  float bcol[4];
  #pragma unroll
  for (int n = 0; n < 4; ++n)
    bcol[n] = bias ? bias[col0 + wc * 64 + n * 16 + lr] : 0.f;
  int rl = tid >> 3, cc = (tid & 7) * 16;

  if (Cf) {
    float* cst = reinterpret_cast<float*>(&lds[0][0][0]);
    #pragma unroll
    for (int m = 0; m < 4; ++m) {
      __syncthreads();
      #pragma unroll
      for (int n = 0; n < 4; ++n)
        #pragma unroll
        for (int j = 0; j < 4; ++j)
          cst[(wr * 16 + lq * 4 + j) * 128 + wc * 64 + n * 16 + lr] = acc[m][n][j] + bcol[n];
      __syncthreads();
      int row = row0 + (rl >> 4) * 64 + m * 16 + (rl & 15);
      if (row < M) {
        float4* dst = reinterpret_cast<float4*>(Cf + (size_t)row * Nn + col0 + cc);
        const float4* src = reinterpret_cast<const float4*>(cst + rl * 128 + cc);
        dst[0] = src[0]; dst[1] = src[1]; dst[2] = src[2]; dst[3] = src[3];
      }
    }
  } else {
    unsigned short* csth = &lds[0][0][0];
    #pragma unroll
    for (int m = 0; m < 4; ++m) {
      __syncthreads();
      #pragma unroll
      for (int n = 0; n < 4; ++n)
        #pragma unroll
        for (int j = 0; j < 4; ++j)
          csth[(wr * 16 + lq * 4 + j) * 128 + wc * 64 + n * 16 + lr] = f2h(acc[m][n][j] + bcol[n]);
      __syncthreads();
      int row = row0 + (rl >> 4) * 64 + m * 16 + (rl & 15);
      if (row < M) {
        int4* dst = reinterpret_cast<int4*>(Ch + (size_t)row * Nn + col0 + cc);
        const int4* src = reinterpret_cast<const int4*>(csth + rl * 128 + cc);
        dst[0] = src[0]; dst[1] = src[1];
      }
    }
  }
}

// -------- pack Q,K (signed int8) + V (excess-128 u8) rows [n][896], scales 3/node --------
__global__ __launch_bounds__(256) void pack_i8_kernel(
    const unsigned short* __restrict__ qkv_s, const unsigned short* __restrict__ qkv_v,
    char* __restrict__ q8, char* __restrict__ k8, unsigned char* __restrict__ v8,
    float* __restrict__ scales)
{
  __shared__ float am[336];
  __shared__ float inv_sh[3];
  int n = blockIdx.x, t = threadIdx.x;
  float va[2][8];

  auto loadChunk = [&](int chunk, float* v) {
    int r = chunk / 112, j = chunk - r * 112;
    int c = j * 8;
    const unsigned short* src;
    if (c < 512) {
      src = qkv_s + (size_t)n * QKV3 + r * 512 + c;
    } else {
      int cc = c - 512, i = cc >> 7, w = cc & 127;
      src = qkv_v + ((size_t)n * 3 + i) * VQKV3 + r * 128 + w;
    }
    int4 sv = *reinterpret_cast<const int4*>(src);
    union { int4 x; unsigned short u[8]; } us; us.x = sv;
    float m = 0.f;
    #pragma unroll
    for (int q = 0; q < 8; ++q) { v[q] = h2f(us.u[q]); m = fmaxf(m, fabsf(v[q])); }
    am[chunk] = m;
  };

  loadChunk(t, va[0]);
  if (t < 80) loadChunk(256 + t, va[1]);
  __syncthreads();

  int lane = t & 63, wid = t >> 6;
  if (wid < 3) {
    int basec = wid * 112;
    float m = am[basec + lane];
    if (lane < 48) m = fmaxf(m, am[basec + 64 + lane]);
    m = wave_max(m);
    if (lane == 0) {
      m = fmaxf(m, 1e-8f);
      scales[3 * n + wid] = m * (1.f / 127.f);
      inv_sh[wid] = 127.f / m;
    }
  }
  __syncthreads();

  auto quantStore = [&](int chunk, const float* v) {
    int r = chunk / 112, j = chunk - r * 112;
    float inv = inv_sh[r];
    int bias = (r == 2) ? 128 : 0;
    unsigned int b0 = 0, b1 = 0;
    #pragma unroll
    for (int q = 0; q < 4; ++q) {
      int x = __float2int_rn(v[q] * inv) + bias;
      b0 |= ((unsigned)(x & 0xff)) << (8 * q);
    }
    #pragma unroll
    for (int q = 0; q < 4; ++q) {
      int x = __float2int_rn(v[4 + q] * inv) + bias;
      b1 |= ((unsigned)(x & 0xff)) << (8 * q);
    }
    char* dst = (r == 0 ? q8 : r == 1 ? k8 : (char*)v8) + (size_t)n * KV8P + j * 8;
    uint2 o; o.x = b0; o.y = b1;
    *reinterpret_cast<uint2*>(dst) = o;
  };

  quantStore(t, va[0]);
  if (t < 80) quantStore(256 + t, va[1]);
}

// -------- single-pass exclusive scan (n <= 10240) --------
__global__ __launch_bounds__(1024) void scan_kernel(const int* __restrict__ counts,
                                                    int* __restrict__ offs, int n) {
  __shared__ int wsum[16];
  const int CH = 10;
  int tid = threadIdx.x, lane = tid & 63, w = tid >> 6;
  int base = tid * CH;
  int v[CH];
  int lsum = 0;
  #pragma unroll
  for (int j = 0; j < CH; ++j) {
    int idx = base + j;
    v[j] = (idx < n) ? counts[idx] : 0;
    lsum += v[j];
  }
  int x = lsum;
  #pragma unroll
  for (int o = 1; o < 64; o <<= 1) {
    int t = __shfl_up(x, o, 64);
    if (lane >= o) x += t;
  }
  if (lane == 63) wsum[w] = x;
  __syncthreads();
  if (tid < 16) {
    int t = wsum[tid];
    #pragma unroll
    for (int o = 1; o < 16; o <<= 1) {
      int u = __shfl_up(t, o, 64);
      if (tid >= o) t += u;
    }
    wsum[tid] = t;
  }
  __syncthreads();
  int excl = ((w > 0) ? wsum[w - 1] : 0) + x - lsum;
  #pragma unroll
  for (int j = 0; j < CH; ++j) {
    int idx = base + j;
    if (idx < n) offs[idx] = excl;
    excl += v[j];
  }
  if (tid == 1023) offs[n] = wsum[15];
}

// -------- scatter: CSR-ordered record (d, row, col) --------
__global__ void scatter_kernel(const int* __restrict__ ei, const float* __restrict__ edge_vec,
                               const int* __restrict__ offs, int* __restrict__ cursor,
                               int4* __restrict__ rec) {
  int e = blockIdx.x * 256 + threadIdx.x;
  if (e < E_EDGES) {
    int row = ei[e], col = ei[E_EDGES + e];
    int pos = offs[row] + atomicAdd(&cursor[row], 1);
    float ex = edge_vec[(size_t)e * 3 + 0];
    float ey = edge_vec[(size_t)e * 3 + 1];
    float ez = edge_vec[(size_t)e * 3 + 2];
    float d = sqrtf(ex * ex + ey * ey + ez * ez);
    rec[pos] = make_int4(__float_as_int(d), row, col, 0);
  }
}

// -------- per-edge logits: CSR order, 8 lanes/edge, int8 sdot4, fused bessel --------
__global__ __launch_bounds__(256, 4) void edge_logits_kernel(
    const char* __restrict__ q8, const char* __restrict__ k8,
    const float* __restrict__ scales, const int4* __restrict__ rec,
    const float* __restrict__ W_edge, const float* __restrict__ b_edge,
    float* __restrict__ logits)
{
  __shared__ float Wl[R_BASIS * H_HEADS];
  Wl[threadIdx.x] = W_edge[threadIdx.x];
  __syncthreads();

  int lane = threadIdx.x & 63;
  int wv = threadIdx.x >> 6;
  int g = lane >> 3, h = lane & 7;
  int pos = blockIdx.x * 32 + wv * 8 + g;
  int4 r = rec[pos];                 // 8 lanes load same 16B -> broadcast
  float d = __int_as_float(r.x);
  int row = r.y, col = r.z;

  const char* qp = q8 + (size_t)row * KV8P;
  const char* kp = k8 + (size_t)col * KV8P;
  uint4 qa[4], ka[4], qv[3], kv[3];
  #pragma unroll
  for (int rr = 0; rr < 4; ++rr)
    ka[rr] = *reinterpret_cast<const uint4*>(kp + h * HD_DIM + rr * 16);
  #pragma unroll
  for (int rr = 0; rr < 3; ++rr)
    kv[rr] = *reinterpret_cast<const uint4*>(kp + 512 + h * 48 + rr * 16);
  #pragma unroll
  for (int rr = 0; rr < 4; ++rr)
    qa[rr] = *reinterpret_cast<const uint4*>(qp + h * HD_DIM + rr * 16);
  #pragma unroll
  for (int rr = 0; rr < 3; ++rr)
    qv[rr] = *reinterpret_cast<const uint4*>(qp + 512 + h * 48 + rr * 16);

  float sq = scales[3 * row + 0];
  float sk = scales[3 * col + 1];

  int dsum = 0;
  #pragma unroll
  for (int rr = 0; rr < 4; ++rr) {
    dsum = SDOT4(qa[rr].x, ka[rr].x, dsum);
    dsum = SDOT4(qa[rr].y, ka[rr].y, dsum);
    dsum = SDOT4(qa[rr].z, ka[rr].z, dsum);
    dsum = SDOT4(qa[rr].w, ka[rr].w, dsum);
  }
  int dvec = 0;
  #pragma unroll
  for (int rr = 0; rr < 3; ++rr) {
    dvec = SDOT4(qv[rr].x, kv[rr].x, dvec);
    dvec = SDOT4(qv[rr].y, kv[rr].y, dvec);
    dvec = SDOT4(qv[rr].z, kv[rr].z, dvec);
    dvec = SDOT4(qv[rr].w, kv[rr].w, dvec);
  }
  dvec += __shfl_xor(dvec, 1, 64);
  dvec += __shfl_xor(dvec, 2, 64);
  dvec += __shfl_xor(dvec, 4, 64);

  float att = sq * sk * ((float)dsum + 0.57735026918962576f * (float)dvec);

  // bessel + edge MLP (4-way-ILP sin recurrence), lane = head column
  float th = d * 0.31415926535897932f;  // pi*d/10
  float s1 = __sinf(th), c1 = __cosf(th);
  float s2 = 2.f * s1 * c1,         c2 = fmaf(c1, c1, -s1 * s1);
  float s3 = fmaf(s2, c1, c2 * s1), c3 = fmaf(c2, c1, -s2 * s1);
  float s4 = 2.f * s2 * c2,         c4 = fmaf(c2, c2, -s2 * s2);
  float sr[4] = {s1, s2, s3, s4};
  float cr[4] = {c1, c2, c3, c4};
  float acc = 0.f;
  #pragma unroll
  for (int t = 0; t < 8; ++t) {
    #pragma unroll
    for (int j = 0; j < 4; ++j) {
      acc = fmaf(sr[j], Wl[(t * 4 + j) * H_HEADS + h], acc);
      float sn = fmaf(sr[j], c4, cr[j] * s4);
      cr[j] = fmaf(cr[j], c4, -sr[j] * s4);
      sr[j] = sn;
    }
  }
  float cut = (d < 10.f) ? 0.5f * (c1 + 1.f) : 0.f;
  float eah = fmaf(acc, cut / fmaxf(d, 1e-8f), b_edge[h]);

  logits[(size_t)pos * H_HEADS + h] = (att + eah) * 0.125f;
}

// -------- per-node softmax + aggregation (excess-128 u8 V, conflict-free) --------
#define MAXDEG 128
__global__ __launch_bounds__(256) void agg_kernel(
    const float* __restrict__ logits, const int4* __restrict__ rec,
    const unsigned char* __restrict__ v8, const float* __restrict__ scales,
    const int* __restrict__ offs,
    unsigned short* __restrict__ out_s, unsigned short* __restrict__ out_v)
{
  __shared__ float buf[3584];        // attn in [0,1024); reduce uses [0,3584)
  __shared__ float av_lds[MAXDEG];
  __shared__ float svc_lds[MAXDEG];
  __shared__ int col_lds[MAXDEG];
  __shared__ float m_sh[H_HEADS], inv_sh[H_HEADS];

  int n = blockIdx.x;
  int beg = offs[n];
  int deg = offs[n + 1] - beg;
  if (deg > MAXDEG) deg = MAXDEG;    // deg ~ Poisson(16); max ~45 for this graph
  int tid = threadIdx.x;
  int lane = tid & 63, wv = tid >> 6;
  int g = lane >> 3, h = lane & 7;

  // Phase 0: stage logits + cols + svc (contiguous, coalesced)
  int cnt8 = deg * 8;
  for (int j = tid; j < cnt8; j += 256) buf[j] = logits[(size_t)beg * 8 + j];
  for (int i = tid; i < deg; i += 256) {
    int c = rec[beg + i].z;
    col_lds[i] = c;
    svc_lds[i] = scales[3 * c + 2];
  }
  __syncthreads();

  // Phase B: softmax on wave 0 (lane=(g,h) -> contiguous addr, conflict-free)
  if (wv == 0) {
    float m = -INFINITY;
    for (int i = g; i < deg; i += 8) m = fmaxf(m, buf[i * 8 + h]);
    m = fmaxf(m, __shfl_xor(m, 8, 64));
    m = fmaxf(m, __shfl_xor(m, 16, 64));
    m = fmaxf(m, __shfl_xor(m, 32, 64));

    float s = 0.f;
    for (int i = g; i < deg; i += 8) {
      float w = __expf(buf[i * 8 + h] - m);
      buf[i * 8 + h] = w;
      s += w;
    }
    s += __shfl_xor(s, 8, 64);
    s += __shfl_xor(s, 16, 64);
    s += __shfl_xor(s, 32, 64);
    float inv = 1.f / (s + 1e-9f);
    if (lane < 8) { m_sh[lane] = m; inv_sh[lane] = inv; }

    for (int i = g; i < deg; i += 8) {
      float t = buf[i * 8 + h] * inv;
      t += __shfl_xor(t, 1, 64);
      t += __shfl_xor(t, 2, 64);
      t += __shfl_xor(t, 4, 64);
      if (h == 0) av_lds[i] = 0.125f * t;
    }
  }
  __syncthreads();

  // Phase C: V-accumulate (4 waves, edges i ≡ wv mod 4); u8 unpack + bias correction
  int hc = lane >> 3;
  float ih = inv_sh[hc];
  float accs[8] = {0,0,0,0,0,0,0,0};
  float accv[8] = {0,0,0,0,0,0,0,0};
  float ws_s = 0.f, ws_v = 0.f;
  auto body = [&](int i) {
    int colv = col_lds[i];
    float svc = svc_lds[i];
    float wgt = buf[i * 8 + hc] * ih * svc;
    float av = av_lds[i] * svc;
    ws_s += wgt; ws_v += av;
    uint2 vs = *reinterpret_cast<const uint2*>(v8 + (size_t)colv * KV8P + lane * 8);
    fma_u8x4(vs.x, wgt, accs);
    fma_u8x4(vs.y, wgt, accs + 4);
    if (lane < 48) {
      uint2 vvl = *reinterpret_cast<const uint2*>(v8 + (size_t)colv * KV8P + 512 + lane * 8);
      fma_u8x4(vvl.x, av, accv);
      fma_u8x4(vvl.y, av, accv + 4);
    }
  };
  int i = wv;
  for (; i + 4 < deg; i += 8) { body(i); body(i + 4); }
  if (i < deg) body(i);
  #pragma unroll
  for (int j = 0; j < 8; ++j) accs[j] = fmaf(-128.f, ws_s, accs[j]);
  if (lane < 48) {
    #pragma unroll
    for (int j = 0; j < 8; ++j) accv[j] = fmaf(-128.f, ws_v, accv[j]);
  }
  __syncthreads();

  // Phase D: cross-wave reduce; write-order swizzle (each b128 pair covers all 8 bank quads)
  float* red_s = buf;                // [4][512]
  float* red_v = buf + 2048;         // [4][384]
  int o = ((lane >> 2) & 1) << 2;    // 0 or 4
  *reinterpret_cast<float4*>(&red_s[wv * 512 + lane * 8 + o]) =
    make_float4(accs[o], accs[o+1], accs[o+2], accs[o+3]);
  *reinterpret_cast<float4*>(&red_s[wv * 512 + lane * 8 + (o ^ 4)]) =
    make_float4(accs[o^4], accs[(o^4)+1], accs[(o^4)+2], accs[(o^4)+3]);
  if (lane < 48) {
    *reinterpret_cast<float4*>(&red_v[wv * 384 + lane * 8 + o]) =
      make_float4(accv[o], accv[o+1], accv[o+2], accv[o+3]);
    *reinterpret_cast<float4*>(&red_v[wv * 384 + lane * 8 + (o ^ 4)]) =
      make_float4(accv[o^4], accv[(o^4)+1], accv[(o^4)+2], accv[(o^4)+3]);
  }
  __syncthreads();

  {
    int d0 = 2 * tid;
    float s0 = red_s[d0] + red_s[512 + d0] + red_s[1024 + d0] + red_s[1536 + d0];
    float s1 = red_s[d0+1] + red_s[512 + d0+1] + red_s[1024 + d0+1] + red_s[1536 + d0+1];
    ushort2 ov; ov.x = f2h(s0); ov.y = f2h(s1);
    *reinterpret_cast<ushort2*>(out_s + (size_t)n * S_DIM + d0) = ov;
  }
  if (tid < 192) {
    int d0 = 2 * tid;
    float s0 = red_v[d0] + red_v[384 + d0] + red_v[768 + d0] + red_v[1152 + d0];
    float s1 = red_v[d0+1] + red_v[384 + d0+1] + red_v[768 + d0+1] + red_v[1152 + d0+1];
    ushort2 ov; ov.x = f2h(s0); ov.y = f2h(s1);
    *reinterpret_cast<ushort2*>(out_v + (size_t)n * NV3 + d0) = ov;
  }
}

// -------- merged epilogue: blocks [0,2500) residual+LN; [2500,7500) vec epilogue --------
__global__ __launch_bounds__(256) void epilogue_kernel(
    const float* __restrict__ x0, const float* __restrict__ dx,
    const float* __restrict__ g, const float* __restrict__ b,
    const float* __restrict__ tmpv, const float* __restrict__ bout_v,
    const float* __restrict__ vectors, float* __restrict__ out_s,
    float* __restrict__ out_v)
{
  __shared__ float l[2][NV3];
  int bidx = blockIdx.x;
  if (bidx < 2500) {
    int r = bidx * 4 + (threadIdx.x >> 6);
    int lane = threadIdx.x & 63;
    float x[8];
    float s = 0.f;
    #pragma unroll
    for (int j = 0; j < 8; ++j) {
      int d = lane + j * 64;
      x[j] = x0[(size_t)r * S_DIM + d] + dx[(size_t)r * S_DIM + d];
      s += x[j];
    }
    #pragma unroll
    for (int o = 32; o > 0; o >>= 1) s += __shfl_xor(s, o, 64);
    float mu = s * (1.f / 512.f);
    float vs = 0.f;
    #pragma unroll
    for (int j = 0; j < 8; ++j) { float t = x[j] - mu; vs += t * t; }
    #pragma unroll
    for (int o = 32; o > 0; o >>= 1) vs += __shfl_xor(vs, o, 64);
    float inv = rsqrtf(vs * (1.f / 512.f) + 1e-5f);
    #pragma unroll
    for (int j = 0; j < 8; ++j) {
      int d = lane + j * 64;
      out_s[(size_t)r * S_DIM + d] = (x[j] - mu) * inv * g[d] + b[d];
    }
  } else {
    int half = threadIdx.x >> 7;        // 0/1
    int t = threadIdx.x & 127;
    int n = (bidx - 2500) * 2 + half;
    #pragma unroll
    for (int i = 0; i < 3; ++i)
      l[half][i * 128 + t] = tmpv[((size_t)n * 3 + i) * V_DIM + t];
    __syncthreads();
    #pragma unroll
    for (int c = 0; c < 3; ++c) {
      int j = t + c * 128;      // j = w*3 + i
      int w = j / 3, i = j - 3 * w;
      out_v[(size_t)n * NV3 + j] = l[half][i * 128 + w] + bout_v[w] + vectors[(size_t)n * NV3 + j];
    }
  }
}

extern "C" void kernel_launch(void* const* d_in, const int* in_sizes, int n_in,
                              void* d_out, int out_size, void* d_ws, size_t ws_size,
                              hipStream_t stream)
{
  (void)in_sizes; (void)n_in; (void)out_size; (void)ws_size;
  const float* scalars  = (const float*)d_in[0];
  const float* vectors  = (const float*)d_in[1];
  const float* edge_vec = (const float*)d_in[2];
  const float* Wq_s = (const float*)d_in[3];
  const float* bq_s = (const float*)d_in[4];
  const float* Wk_s = (const float*)d_in[5];
  const float* bk_s = (const float*)d_in[6];
  const float* Wv_s = (const float*)d_in[7];
  const float* bv_s = (const float*)d_in[8];
  const float* Wq_v = (const float*)d_in[9];
  const float* Wk_v = (const float*)d_in[10];
  const float* Wv_v = (const float*)d_in[11];
  const float* Wout_s = (const float*)d_in[12];
  const float* bout_s = (const float*)d_in[13];
  const float* Wout_v = (const float*)d_in[14];
  const float* bout_v = (const float*)d_in[15];
  const float* W_edge = (const float*)d_in[16];
  const float* b_edge = (const float*)d_in[17];
  const float* ln_g = (const float*)d_in[18];
  const float* ln_b = (const float*)d_in[19];
  const int* ei = (const int*)d_in[20];

  float* out = (float*)d_out;
  const size_t NS  = (size_t)N_NODES * S_DIM;     // 5,120,000
  const size_t NVs = (size_t)N_NODES * NV3;       // 3,840,000
  const size_t EH  = (size_t)E_EDGES * H_HEADS;   // 1,280,000
  const size_t WSZ = (size_t)S_DIM * S_DIM;
  const size_t WVZ = (size_t)V_DIM * V_DIM;
  const int MV = N_NODES * 3;

  char* base = (char*)d_ws;
  auto carve = [&](size_t bytes) -> char* {
    char* p = base;
    base += (bytes + 255) & ~(size_t)255;
    return p;
  };
  unsigned short* Af16 = (unsigned short*)carve(NS * 2);    // 10.24MB
  unsigned short* VT0  = (unsigned short*)carve(NVs * 2);   // 7.68MB
  float* tmpv = (float*)Af16;   // alias (15.36MB; Af16+VT0 dead by then)
  unsigned char* v8 = (unsigned char*)Af16;  // alias: lifetime pack->agg, before tmpv written
  unsigned short* qkv_s = (unsigned short*)carve((size_t)N_NODES * QKV3 * 2);   // 30.72MB
  unsigned short* qkv_v = (unsigned short*)carve((size_t)MV * VQKV3 * 2);       // 23.04MB
  unsigned short* outs_pre = (unsigned short*)carve(NS * 2);
  unsigned short* outv_pre = (unsigned short*)carve(NVs * 2);
  float* dx       = (float*)carve(NS * 4);        // 20.48MB
  // q8/k8 alias dx: lifetimes disjoint (pack->agg; dx written by Wout gemm after)
  char* q8 = (char*)dx;                                      // 8.96MB
  char* k8 = q8 + (size_t)N_NODES * KV8P;                    // 8.96MB (17.92 <= 20.48)
  float* logitsS  = (float*)carve(EH * 4);
  int4*  rec      = (int4*)carve((size_t)E_EDGES * 16);      // 2.56MB
  unsigned short* WqkvT  = (unsigned short*)carve(3 * WSZ * 2);
  unsigned short* WoT    = (unsigned short*)carve(WSZ * 2);
  unsigned short* WqkvvT = (unsigned short*)carve(3 * WVZ * 2);
  unsigned short* WovT   = (unsigned short*)carve(WVZ * 2);
  float* bias_cat = (float*)carve(QKV3 * 4);
  float* scales   = (float*)carve(3 * N_NODES * 4);
  int* counts = (int*)carve(N_NODES * 4);
  int* offs   = (int*)carve((N_NODES + 1) * 4);
  int* cursor = (int*)carve(N_NODES * 4);

  hipMemsetAsync(counts, 0, N_NODES * sizeof(int), stream);
  hipMemsetAsync(cursor, 0, N_NODES * sizeof(int), stream);

  // fused prep: f32->f16 scalars | edge count | bias concat
  prep_kernel<<<5631, 256, 0, stream>>>(scalars, Af16, ei, counts,
                                        bq_s, bk_s, bv_s, bias_cat);
  dim3 tBlk(32, 8);
  transpose4_kernel<<<dim3(16, 16, 4), tBlk, 0, stream>>>(Wq_s, Wk_s, Wv_s, Wout_s, WqkvT, WoT, S_DIM);
  transpose4_kernel<<<dim3(4, 4, 4), tBlk, 0, stream>>>(Wq_v, Wk_v, Wv_v, Wout_v, WqkvvT, WovT, V_DIM);
  vec_transpose_kernel<<<N_NODES, 128, 0, stream>>>(vectors, VT0);

  // fused QKV projections
  gemm_f16_kernel<<<dim3(QKV3 / 128, (N_NODES + 127) / 128), 256, 0, stream>>>(
      Af16, WqkvT, bias_cat, nullptr, qkv_s, N_NODES, S_DIM, QKV3);
  gemm_f16_kernel<<<dim3(VQKV3 / 128, (MV + 127) / 128), 256, 0, stream>>>(
      VT0, WqkvvT, nullptr, nullptr, qkv_v, MV, V_DIM, VQKV3);

  // int8 Q/K + excess-128 V rows + per-node scales (v8 overwrites dead Af16 region)
  pack_i8_kernel<<<N_NODES, 256, 0, stream>>>(qkv_s, qkv_v, q8, k8, v8, scales);

  // CSR offsets + CSR-ordered edge records
  scan_kernel<<<1, 1024, 0, stream>>>(counts, offs, N_NODES);
  scatter_kernel<<<(E_EDGES + 255) / 256, 256, 0, stream>>>(ei, edge_vec, offs, cursor, rec);

  // edge logits (int8 sdot4 gathers + fused bessel, CSR order)
  edge_logits_kernel<<<E_EDGES / 32, 256, 0, stream>>>(q8, k8, scales, rec,
                                                       W_edge, b_edge, logitsS);

  // softmax + aggregate (excess-128 u8 V gather)
  agg_kernel<<<N_NODES, 256, 0, stream>>>(logitsS, rec, v8, scales, offs,
                                          outs_pre, outv_pre);

  // output projections + merged epilogue
  gemm_f16_kernel<<<dim3(S_DIM / 128, (N_NODES + 127) / 128), 256, 0, stream>>>(
      outs_pre, WoT, bout_s, dx, nullptr, N_NODES, S_DIM, S_DIM);
  gemm_f16_kernel<<<dim3(1, (MV + 127) / 128), 256, 0, stream>>>(
      outv_pre, WovT, nullptr, tmpv, nullptr, MV, V_DIM, V_DIM);
  epilogue_kernel<<<7500, 256, 0, stream>>>(scalars, dx, ln_g, ln_b,
                                            tmpv, bout_v, vectors, out, out + NS);
}